// Round 1
// baseline (525.856 us; speedup 1.0000x reference)
//
#include <hip/hip_runtime.h>
#include <hip/hip_bf16.h>
#include <math.h>

#define NUM_TOKENS 16384
#define HIDDEN 4096
#define NUM_EXPERTS 256
#define TOP_K 8
#define N_GROUP 8
#define GROUP_SIZE (NUM_EXPERTS / N_GROUP)   // 32
#define TOPK_GROUP 4

// ---------------- GEMM: logits = H @ W^T  (fp32, vector ALU) ----------------
// H: [T, K] row-major, W: [E, K] row-major -> C[t][e] = dot(H[t,:], W[e,:])
// Tile: BM=64 tokens x BN=64 experts x BK=16, 256 threads, 4x4 acc per thread.
#define BM 64
#define BN 64
#define BK 16

__global__ __launch_bounds__(256) void gemm_f32_kernel(
    const float* __restrict__ A, const float* __restrict__ B, float* __restrict__ C)
{
    __shared__ float As[BK][BM];
    __shared__ float Bs[BK][BN];

    const int bm = blockIdx.x;           // 0..255
    const int bn = blockIdx.y;           // 0..3
    const int tid = threadIdx.x;
    const int tm = tid & 15;             // 0..15 -> rows tm*4..tm*4+3
    const int tn = tid >> 4;             // 0..15 -> cols tn*4..tn*4+3

    const int row0 = bm * BM;
    const int col0 = bn * BN;

    // staging indices: each thread loads one float4 of A and one of B
    const int lr = tid >> 2;             // 0..63 (row within tile)
    const int lc = (tid & 3) * 4;        // 0,4,8,12 (col within BK)

    float acc[4][4];
    #pragma unroll
    for (int i = 0; i < 4; ++i)
        #pragma unroll
        for (int j = 0; j < 4; ++j) acc[i][j] = 0.f;

    const float* aptr = A + (size_t)(row0 + lr) * HIDDEN + lc;
    const float* bptr = B + (size_t)(col0 + lr) * HIDDEN + lc;

    for (int k0 = 0; k0 < HIDDEN; k0 += BK) {
        const float4 a = *(const float4*)(aptr + k0);
        const float4 b = *(const float4*)(bptr + k0);
        __syncthreads();   // previous iteration's LDS reads complete
        As[lc + 0][lr] = a.x; As[lc + 1][lr] = a.y;
        As[lc + 2][lr] = a.z; As[lc + 3][lr] = a.w;
        Bs[lc + 0][lr] = b.x; Bs[lc + 1][lr] = b.y;
        Bs[lc + 2][lr] = b.z; Bs[lc + 3][lr] = b.w;
        __syncthreads();   // writes visible
        #pragma unroll
        for (int k = 0; k < BK; ++k) {
            const float4 av = *(const float4*)&As[k][tm * 4];
            const float4 bv = *(const float4*)&Bs[k][tn * 4];
            const float am[4] = {av.x, av.y, av.z, av.w};
            const float bm_[4] = {bv.x, bv.y, bv.z, bv.w};
            #pragma unroll
            for (int i = 0; i < 4; ++i)
                #pragma unroll
                for (int j = 0; j < 4; ++j)
                    acc[i][j] = fmaf(am[i], bm_[j], acc[i][j]);
        }
    }

    #pragma unroll
    for (int i = 0; i < 4; ++i) {
        float4 v = make_float4(acc[i][0], acc[i][1], acc[i][2], acc[i][3]);
        *(float4*)&C[(size_t)(row0 + tm * 4 + i) * NUM_EXPERTS + col0 + tn * 4] = v;
    }
}

// ---------------- Router: per-token top-k with jax.lax.top_k tie semantics ---
// One wave (64 lanes) per token; lane l owns experts 4l..4l+3.
// Group g (32 experts) == lanes 8g..8g+7 (contiguous, shfl_xor stays in group).
__global__ __launch_bounds__(256) void router_topk_kernel(
    const float* __restrict__ logits, const float* __restrict__ bias,
    float* __restrict__ out_w, float* __restrict__ out_i)
{
    const int wid  = threadIdx.x >> 6;
    const int lane = threadIdx.x & 63;
    const int token = blockIdx.x * 4 + wid;

    const float* row = logits + (size_t)token * NUM_EXPERTS;
    const float4 lg = *(const float4*)&row[lane * 4];

    float sig[4], sc[4];
    {
        const float l4[4] = {lg.x, lg.y, lg.z, lg.w};
        #pragma unroll
        for (int j = 0; j < 4; ++j) {
            sig[j] = 1.f / (1.f + expf(-l4[j]));
            sc[j]  = sig[j] + bias[lane * 4 + j];
        }
    }

    // --- top-2 sum within each group of 32 experts (8 lanes x 4) ---
    float m1 = sc[0], m2 = -INFINITY;
    #pragma unroll
    for (int j = 1; j < 4; ++j) {
        if (sc[j] > m1) { m2 = m1; m1 = sc[j]; }
        else if (sc[j] > m2) { m2 = sc[j]; }
    }
    #pragma unroll
    for (int off = 1; off < 8; off <<= 1) {
        const float o1 = __shfl_xor(m1, off);
        const float o2 = __shfl_xor(m2, off);
        const float lo = fminf(m1, o1);
        m1 = fmaxf(m1, o1);
        m2 = fmaxf(lo, fmaxf(m2, o2));
    }
    const float gscore = m1 + m2;   // all 8 lanes of a group hold group score

    // --- select top-4 groups (rank with lower-index tie-break) ---
    const int gmy = lane >> 3;
    int rank = 0;
    #pragma unroll
    for (int g = 0; g < N_GROUP; ++g) {
        const float gs = __shfl(gscore, g * 8);
        if (gs > gscore || (gs == gscore && g < gmy)) ++rank;
    }
    if (rank >= TOPK_GROUP) {
        #pragma unroll
        for (int j = 0; j < 4; ++j) sc[j] = -INFINITY;
    }

    // --- top-8 experts over masked scores_for_choice ---
    float wk[TOP_K]; int ik[TOP_K];
    float wsum = 0.f;
    #pragma unroll
    for (int k = 0; k < TOP_K; ++k) {
        float bv = sc[0]; int bi = lane * 4;
        #pragma unroll
        for (int j = 1; j < 4; ++j)
            if (sc[j] > bv) { bv = sc[j]; bi = lane * 4 + j; }
        #pragma unroll
        for (int off = 1; off < 64; off <<= 1) {
            const float v2 = __shfl_xor(bv, off);
            const int   i2 = __shfl_xor(bi, off);
            if (v2 > bv || (v2 == bv && i2 < bi)) { bv = v2; bi = i2; }
        }
        // bv/bi now uniform: global max with lowest index on ties
        const int owner = bi >> 2;
        const int j = bi & 3;   // uniform
        const float sv = (j == 0) ? sig[0] : (j == 1) ? sig[1] : (j == 2) ? sig[2] : sig[3];
        const float w = __shfl(sv, owner);
        wk[k] = w; ik[k] = bi; wsum += w;
        if (lane == owner) {
            if (j == 0) sc[0] = -INFINITY;
            else if (j == 1) sc[1] = -INFINITY;
            else if (j == 2) sc[2] = -INFINITY;
            else sc[3] = -INFINITY;
        }
    }

    if (lane == 0) {
        const float denom = wsum + 1e-20f;
        #pragma unroll
        for (int k = 0; k < TOP_K; ++k) {
            out_w[(size_t)token * TOP_K + k] = wk[k] / denom;   // scaling factor 1.0
            out_i[(size_t)token * TOP_K + k] = (float)ik[k];
        }
    }
}

extern "C" void kernel_launch(void* const* d_in, const int* in_sizes, int n_in,
                              void* d_out, int out_size, void* d_ws, size_t ws_size,
                              hipStream_t stream) {
    const float* hidden = (const float*)d_in[0];
    const float* weight = (const float*)d_in[1];
    const float* bias   = (const float*)d_in[2];

    float* logits = (float*)d_out;                                   // [T, E]
    float* out_w  = logits + (size_t)NUM_TOKENS * NUM_EXPERTS;       // [T, 8]
    float* out_i  = out_w + (size_t)NUM_TOKENS * TOP_K;              // [T, 8] (as float)

    dim3 ggrid(NUM_TOKENS / BM, NUM_EXPERTS / BN);
    gemm_f32_kernel<<<ggrid, 256, 0, stream>>>(hidden, weight, logits);

    router_topk_kernel<<<NUM_TOKENS / 4, 256, 0, stream>>>(logits, bias, out_w, out_i);
}

// Round 2
// 186.320 us; speedup vs baseline: 2.8223x; 2.8223x over previous
//
#include <hip/hip_runtime.h>
#include <hip/hip_bf16.h>
#include <math.h>

#define TKN 16384
#define HID 4096
#define NE  256
#define TOPK 8
#define NGRP 8
#define TOPG 4

#define BM 128
#define BN 128
#define BKT 64            // K elements staged per tile
#define NKT (HID / BKT)   // 64 K-steps

typedef _Float16 half8 __attribute__((ext_vector_type(8)));
typedef float    f32x4 __attribute__((ext_vector_type(4)));

static __device__ __forceinline__ unsigned pkrtz(float x, float y) {
    auto r = __builtin_amdgcn_cvt_pkrtz(x, y);   // v_cvt_pkrtz_f16_f32
    return __builtin_bit_cast(unsigned, r);
}
// top 11 significand bits of a fp32 — exactly representable in f16 (normal range)
static __device__ __forceinline__ float hi_mask(float a) {
    return __uint_as_float(__float_as_uint(a) & 0xFFFFE000u);
}

// split 16 fp32 into hi/lo f16 planes and store swizzled into LDS
static __device__ __forceinline__ void split_store_16(
    const float4* p, unsigned char* hiPlane, unsigned char* loPlane,
    int srow, int skq)
{
    float e[16];
    #pragma unroll
    for (int i = 0; i < 4; ++i) {
        e[i*4+0] = p[i].x; e[i*4+1] = p[i].y; e[i*4+2] = p[i].z; e[i*4+3] = p[i].w;
    }
    unsigned hw[8], lw[8];
    #pragma unroll
    for (int j = 0; j < 8; ++j) {
        const float x0 = e[2*j], x1 = e[2*j+1];
        const float h0 = hi_mask(x0), h1 = hi_mask(x1);
        hw[j] = pkrtz(h0, h1);
        lw[j] = pkrtz(x0 - h0, x1 - h1);
    }
    #pragma unroll
    for (int c = 0; c < 2; ++c) {
        const int ad = srow * 128 + (((skq * 2) + c * 16) ^ ((srow & 7) << 4));
        *(uint4*)&hiPlane[ad] = make_uint4(hw[c*4+0], hw[c*4+1], hw[c*4+2], hw[c*4+3]);
        *(uint4*)&loPlane[ad] = make_uint4(lw[c*4+0], lw[c*4+1], lw[c*4+2], lw[c*4+3]);
    }
}

// logits = A[T,H] @ B[E,H]^T via fp16x2 split (3 MFMA products, fp32 accumulate)
__global__ __launch_bounds__(512, 2) void gemm_split_f16(
    const float* __restrict__ A, const float* __restrict__ Bw, float* __restrict__ C)
{
    // [buf][plane: 0=A-hi 1=A-lo 2=B-hi 3=B-lo][128 rows x 128 bytes]
    __shared__ __align__(16) unsigned char smem[2][4][BM * BKT * 2];   // 128 KiB

    const int tid  = threadIdx.x;
    const int lane = tid & 63;
    const int wave = tid >> 6;
    const int wg   = wave >> 2;          // k-half owner (split-K in block)
    const int wr   = (wave >> 1) & 1;    // wave row quadrant
    const int wc   = wave & 1;           // wave col quadrant

    const int row0 = blockIdx.y * BM;
    const int col0 = blockIdx.x * BN;

    // staging: thread covers 16 contiguous k of one row, for A and for B
    const int srow = tid >> 2;           // 0..127
    const int skq  = (tid & 3) * 16;     // 0,16,32,48

    const float* aG = A  + (size_t)(row0 + srow) * HID + skq;
    const float* bG = Bw + (size_t)(col0 + srow) * HID + skq;

    f32x4 acc[16];
    #pragma unroll
    for (int i = 0; i < 16; ++i) acc[i] = (f32x4)0.f;

    float4 pa[4], pb[4];

    // prologue: load + stage k-tile 0 into buf 0
    #pragma unroll
    for (int i = 0; i < 4; ++i) {
        pa[i] = *(const float4*)(aG + i * 4);
        pb[i] = *(const float4*)(bG + i * 4);
    }
    split_store_16(pa, &smem[0][0][0], &smem[0][1][0], srow, skq);
    split_store_16(pb, &smem[0][2][0], &smem[0][3][0], srow, skq);
    __syncthreads();

    for (int kt = 0; kt < NKT; ++kt) {
        const int cur = kt & 1;

        // issue next tile's global loads early (latency hides under MFMA)
        if (kt + 1 < NKT) {
            const float* ap = aG + (size_t)(kt + 1) * BKT;
            const float* bp = bG + (size_t)(kt + 1) * BKT;
            #pragma unroll
            for (int i = 0; i < 4; ++i) {
                pa[i] = *(const float4*)(ap + i * 4);
                pb[i] = *(const float4*)(bp + i * 4);
            }
        }

        // compute this wave's k-half from buf cur
        {
            const int kbyte = wg * 64 + ((lane >> 4) << 4);
            half8 af[4][2], bf[4][2];
            #pragma unroll
            for (int mt = 0; mt < 4; ++mt) {
                const int m  = wr * 64 + mt * 16 + (lane & 15);
                const int ad = m * 128 + (kbyte ^ ((m & 7) << 4));
                af[mt][0] = *(const half8*)&smem[cur][0][ad];
                af[mt][1] = *(const half8*)&smem[cur][1][ad];
            }
            #pragma unroll
            for (int nt = 0; nt < 4; ++nt) {
                const int n  = wc * 64 + nt * 16 + (lane & 15);
                const int ad = n * 128 + (kbyte ^ ((n & 7) << 4));
                bf[nt][0] = *(const half8*)&smem[cur][2][ad];
                bf[nt][1] = *(const half8*)&smem[cur][3][ad];
            }
            #pragma unroll
            for (int mt = 0; mt < 4; ++mt)
                #pragma unroll
                for (int nt = 0; nt < 4; ++nt) {
                    f32x4 c = acc[mt*4+nt];
                    c = __builtin_amdgcn_mfma_f32_16x16x32_f16(af[mt][0], bf[nt][0], c, 0, 0, 0);
                    c = __builtin_amdgcn_mfma_f32_16x16x32_f16(af[mt][0], bf[nt][1], c, 0, 0, 0);
                    c = __builtin_amdgcn_mfma_f32_16x16x32_f16(af[mt][1], bf[nt][0], c, 0, 0, 0);
                    acc[mt*4+nt] = c;
                }
        }

        // stage next tile into the other buffer
        if (kt + 1 < NKT) {
            const int nb = (kt + 1) & 1;
            split_store_16(pa, &smem[nb][0][0], &smem[nb][1][0], srow, skq);
            split_store_16(pb, &smem[nb][2][0], &smem[nb][3][0], srow, skq);
        }
        __syncthreads();
    }

    // ---- epilogue: reduce the two k-half wave groups through LDS, store C ----
    __syncthreads();
    unsigned char* red = &smem[0][0][0];
    const int rbase = (wr * 2 + wc) * 16384;
    if (wg == 1) {
        #pragma unroll
        for (int f = 0; f < 16; ++f) {
            const int ad = rbase + ((lane * 256 + f * 16) ^ ((lane & 7) << 4));
            *(f32x4*)&red[ad] = acc[f];
        }
    }
    __syncthreads();
    if (wg == 0) {
        #pragma unroll
        for (int mt = 0; mt < 4; ++mt) {
            #pragma unroll
            for (int nt = 0; nt < 4; ++nt) {
                const int f  = mt * 4 + nt;
                const int ad = rbase + ((lane * 256 + f * 16) ^ ((lane & 7) << 4));
                f32x4 o = acc[f] + *(const f32x4*)&red[ad];
                const int r0 = row0 + wr * 64 + mt * 16 + ((lane >> 4) << 2);
                const int cc = col0 + wc * 64 + nt * 16 + (lane & 15);
                #pragma unroll
                for (int r = 0; r < 4; ++r)
                    C[(size_t)(r0 + r) * NE + cc] = o[r];
            }
        }
    }
}

// ---------------- Router: per-token top-k (unchanged, passed round 1) --------
__global__ __launch_bounds__(256) void router_topk_kernel(
    const float* __restrict__ logits, const float* __restrict__ bias,
    float* __restrict__ out_w, float* __restrict__ out_i)
{
    const int wid  = threadIdx.x >> 6;
    const int lane = threadIdx.x & 63;
    const int token = blockIdx.x * 4 + wid;

    const float* row = logits + (size_t)token * NE;
    const float4 lg = *(const float4*)&row[lane * 4];

    float sig[4], sc[4];
    {
        const float l4[4] = {lg.x, lg.y, lg.z, lg.w};
        #pragma unroll
        for (int j = 0; j < 4; ++j) {
            sig[j] = 1.f / (1.f + expf(-l4[j]));
            sc[j]  = sig[j] + bias[lane * 4 + j];
        }
    }

    // top-2 sum within each group of 32 experts (8 lanes x 4)
    float m1 = sc[0], m2 = -INFINITY;
    #pragma unroll
    for (int j = 1; j < 4; ++j) {
        if (sc[j] > m1) { m2 = m1; m1 = sc[j]; }
        else if (sc[j] > m2) { m2 = sc[j]; }
    }
    #pragma unroll
    for (int off = 1; off < 8; off <<= 1) {
        const float o1 = __shfl_xor(m1, off);
        const float o2 = __shfl_xor(m2, off);
        const float lo = fminf(m1, o1);
        m1 = fmaxf(m1, o1);
        m2 = fmaxf(lo, fmaxf(m2, o2));
    }
    const float gscore = m1 + m2;

    // select top-4 groups (lower group index wins ties)
    const int gmy = lane >> 3;
    int rank = 0;
    #pragma unroll
    for (int g = 0; g < NGRP; ++g) {
        const float gs = __shfl(gscore, g * 8);
        if (gs > gscore || (gs == gscore && g < gmy)) ++rank;
    }
    if (rank >= TOPG) {
        #pragma unroll
        for (int j = 0; j < 4; ++j) sc[j] = -INFINITY;
    }

    // top-8 experts over masked scores (lower expert index wins ties)
    float wk[TOPK]; int ik[TOPK];
    float wsum = 0.f;
    #pragma unroll
    for (int k = 0; k < TOPK; ++k) {
        float bv = sc[0]; int bi = lane * 4;
        #pragma unroll
        for (int j = 1; j < 4; ++j)
            if (sc[j] > bv) { bv = sc[j]; bi = lane * 4 + j; }
        #pragma unroll
        for (int off = 1; off < 64; off <<= 1) {
            const float v2 = __shfl_xor(bv, off);
            const int   i2 = __shfl_xor(bi, off);
            if (v2 > bv || (v2 == bv && i2 < bi)) { bv = v2; bi = i2; }
        }
        const int owner = bi >> 2;
        const int j = bi & 3;
        const float sv = (j == 0) ? sig[0] : (j == 1) ? sig[1] : (j == 2) ? sig[2] : sig[3];
        const float w = __shfl(sv, owner);
        wk[k] = w; ik[k] = bi; wsum += w;
        if (lane == owner) {
            if (j == 0) sc[0] = -INFINITY;
            else if (j == 1) sc[1] = -INFINITY;
            else if (j == 2) sc[2] = -INFINITY;
            else sc[3] = -INFINITY;
        }
    }

    if (lane == 0) {
        const float denom = wsum + 1e-20f;
        #pragma unroll
        for (int k = 0; k < TOPK; ++k) {
            out_w[(size_t)token * TOPK + k] = wk[k] / denom;
            out_i[(size_t)token * TOPK + k] = (float)ik[k];
        }
    }
}

extern "C" void kernel_launch(void* const* d_in, const int* in_sizes, int n_in,
                              void* d_out, int out_size, void* d_ws, size_t ws_size,
                              hipStream_t stream) {
    const float* hidden = (const float*)d_in[0];
    const float* weight = (const float*)d_in[1];
    const float* bias   = (const float*)d_in[2];

    float* logits = (float*)d_out;                              // [T, E]
    float* out_w  = logits + (size_t)TKN * NE;                  // [T, 8]
    float* out_i  = out_w + (size_t)TKN * TOPK;                 // [T, 8]

    dim3 ggrid(NE / BN, TKN / BM);     // (2, 128): both expert-blocks of a row co-resident
    gemm_split_f16<<<ggrid, 512, 0, stream>>>(hidden, weight, logits);

    router_topk_kernel<<<TKN / 4, 256, 0, stream>>>(logits, bias, out_w, out_i);
}

// Round 3
// 150.067 us; speedup vs baseline: 3.5041x; 1.2416x over previous
//
#include <hip/hip_runtime.h>
#include <hip/hip_bf16.h>
#include <math.h>

#define TKN 16384
#define HID 4096
#define NE  256
#define TOPK 8
#define NGRP 8
#define TOPG 4

#define BM 128
#define BN 128
#define BK 64
#define NKT (HID / BK)          // 64 K-steps

#define ASTR 144                // A f16-plane row stride in bytes (128 data + 16 pad)
#define APL  (BM * ASTR)        // 18432 B per A plane
#define BPL  (BN * 128)         // 16384 B per B plane (swizzled, dense)
#define BIMG (2 * BPL)          // 32 KB staged B image per (cb,kt)

typedef _Float16 half8 __attribute__((ext_vector_type(8)));
typedef float    f32x4 __attribute__((ext_vector_type(4)));

static __device__ __forceinline__ unsigned pkrtz(float x, float y) {
    auto r = __builtin_amdgcn_cvt_pkrtz(x, y);   // v_cvt_pkrtz_f16_f32
    return __builtin_bit_cast(unsigned, r);
}
// top bits of fp32 exactly representable in f16 (normal range)
static __device__ __forceinline__ float hi_mask(float a) {
    return __uint_as_float(__float_as_uint(a) & 0xFFFFE000u);
}

// ---- prep: B [256][4096] f32 -> pre-swizzled f16 hi/lo LDS images in ws ----
// ws[(cb*64+kt)*32768 + pl*16384 + row*128 + (kbyte ^ ((row&7)<<4))]
__global__ __launch_bounds__(256) void prep_b(const float* __restrict__ B,
                                              unsigned char* __restrict__ ws)
{
    const int gid = blockIdx.x * 256 + threadIdx.x;   // 131072 total
    const int e   = gid >> 9;          // expert 0..255
    const int k0  = (gid & 511) * 8;   // k chunk of 8
    const float* src = B + (size_t)e * HID + k0;
    float v[8];
    #pragma unroll
    for (int i = 0; i < 8; ++i) v[i] = src[i];
    unsigned hw[4], lw[4];
    #pragma unroll
    for (int j = 0; j < 4; ++j) {
        const float x0 = v[2*j], x1 = v[2*j+1];
        const float h0 = hi_mask(x0), h1 = hi_mask(x1);
        hw[j] = pkrtz(h0, h1);
        lw[j] = pkrtz(x0 - h0, x1 - h1);
    }
    const int cb  = e >> 7;
    const int row = e & 127;
    const int kt  = k0 >> 6;
    const int x   = ((k0 & 63) * 2) ^ ((row & 7) << 4);
    unsigned char* img = ws + (size_t)(cb * NKT + kt) * BIMG + row * 128 + x;
    *(uint4*)(img)       = make_uint4(hw[0], hw[1], hw[2], hw[3]);
    *(uint4*)(img + BPL) = make_uint4(lw[0], lw[1], lw[2], lw[3]);
}

// ---- GEMM: logits = A[T,H] @ B[E,H]^T, f16x2 split, 3 MFMA passes ----------
__global__ __launch_bounds__(1024, 4) void gemm_mfma(
    const float* __restrict__ A, const unsigned char* __restrict__ Bws,
    float* __restrict__ C)
{
    __shared__ __align__(16) unsigned char sA[2][2][APL];   // 72 KB
    __shared__ __align__(16) unsigned char sB[2][BIMG];     // 64 KB

    const int tid  = threadIdx.x;
    const int lane = tid & 63;
    const int wave = tid >> 6;
    const int wg = wave >> 3;           // k-half
    const int wr = (wave >> 2) & 1;     // row 64-half
    const int wc = wave & 3;            // col 32-quarter

    // XCD-aware remap: cb-twins (same A panel) land adjacent on one XCD
    const int bid  = blockIdx.x;                 // 0..255
    const int mb   = (bid & 7) * 16 + (bid >> 4);
    const int cb   = (bid >> 3) & 1;
    const int row0 = mb * BM;

    // A staging: thread covers two float4 chunks (rows r and r+64)
    const int arow = tid >> 4;                   // 0..63
    const int acol = (tid & 15) * 4;             // float idx 0..60
    const float* aG0 = A + (size_t)(row0 + arow) * HID + acol;
    const float* aG1 = aG0 + (size_t)64 * HID;
    const int aw0 = arow * ASTR + acol * 2;      // f16-plane byte addr
    const int aw1 = (arow + 64) * ASTR + acol * 2;

    // B staging: verbatim 2x16B per thread
    const unsigned char* bG = Bws + (size_t)cb * NKT * BIMG + tid * 16;
    const int bw0 = tid * 16, bw1 = 16384 + tid * 16;

    // fragment read offsets
    const int afr = wr * 64 + (lane & 15);                   // + mt*16
    const int afo = afr * ASTR + (wg * 4 + (lane >> 4)) * 16;
    const int bfr = wc * 32 + (lane & 15);                   // + nt*16
    const int bfx = (wg * 4 + (lane >> 4)) * 16;

    f32x4 acc[4][2];
    #pragma unroll
    for (int i = 0; i < 4; ++i) { acc[i][0] = (f32x4)0.f; acc[i][1] = (f32x4)0.f; }

    float4 av0, av1; uint4 bv0, bv1;

    // prologue: load + stage k-tile 0 into buf 0
    av0 = *(const float4*)(aG0);
    av1 = *(const float4*)(aG1);
    bv0 = *(const uint4*)(bG);
    bv1 = *(const uint4*)(bG + 16384);
    {
        const float h0 = hi_mask(av0.x), h1 = hi_mask(av0.y),
                    h2 = hi_mask(av0.z), h3 = hi_mask(av0.w);
        *(uint2*)&sA[0][0][aw0] = make_uint2(pkrtz(h0, h1), pkrtz(h2, h3));
        *(uint2*)&sA[0][1][aw0] = make_uint2(pkrtz(av0.x - h0, av0.y - h1),
                                             pkrtz(av0.z - h2, av0.w - h3));
        const float g0 = hi_mask(av1.x), g1 = hi_mask(av1.y),
                    g2 = hi_mask(av1.z), g3 = hi_mask(av1.w);
        *(uint2*)&sA[0][0][aw1] = make_uint2(pkrtz(g0, g1), pkrtz(g2, g3));
        *(uint2*)&sA[0][1][aw1] = make_uint2(pkrtz(av1.x - g0, av1.y - g1),
                                             pkrtz(av1.z - g2, av1.w - g3));
        *(uint4*)&sB[0][bw0] = bv0;
        *(uint4*)&sB[0][bw1] = bv1;
    }
    __syncthreads();

    for (int kt = 0; kt < NKT; ++kt) {
        const int cur = kt & 1;
        const bool more = (kt + 1 < NKT);
        // issue next-tile loads early (latency hides under MFMA section)
        if (more) {
            av0 = *(const float4*)(aG0 + (kt + 1) * BK);
            av1 = *(const float4*)(aG1 + (kt + 1) * BK);
            const unsigned char* bp = bG + (size_t)(kt + 1) * BIMG;
            bv0 = *(const uint4*)(bp);
            bv1 = *(const uint4*)(bp + 16384);
        }
        // compute current buffer
        {
            half8 bf[2][2];
            #pragma unroll
            for (int nt = 0; nt < 2; ++nt) {
                const int r  = bfr + nt * 16;
                const int ad = r * 128 + (bfx ^ ((r & 7) << 4));
                bf[nt][0] = *(const half8*)&sB[cur][ad];
                bf[nt][1] = *(const half8*)&sB[cur][BPL + ad];
            }
            #pragma unroll
            for (int mt = 0; mt < 4; ++mt) {
                const int ad = afo + mt * 16 * ASTR;
                const half8 ah = *(const half8*)&sA[cur][0][ad];
                const half8 al = *(const half8*)&sA[cur][1][ad];
                #pragma unroll
                for (int nt = 0; nt < 2; ++nt) {
                    f32x4 c = acc[mt][nt];
                    c = __builtin_amdgcn_mfma_f32_16x16x32_f16(ah, bf[nt][0], c, 0, 0, 0);
                    c = __builtin_amdgcn_mfma_f32_16x16x32_f16(ah, bf[nt][1], c, 0, 0, 0);
                    c = __builtin_amdgcn_mfma_f32_16x16x32_f16(al, bf[nt][0], c, 0, 0, 0);
                    acc[mt][nt] = c;
                }
            }
        }
        // stage next tile into the other buffer
        if (more) {
            const int nb = cur ^ 1;
            const float h0 = hi_mask(av0.x), h1 = hi_mask(av0.y),
                        h2 = hi_mask(av0.z), h3 = hi_mask(av0.w);
            *(uint2*)&sA[nb][0][aw0] = make_uint2(pkrtz(h0, h1), pkrtz(h2, h3));
            *(uint2*)&sA[nb][1][aw0] = make_uint2(pkrtz(av0.x - h0, av0.y - h1),
                                                  pkrtz(av0.z - h2, av0.w - h3));
            const float g0 = hi_mask(av1.x), g1 = hi_mask(av1.y),
                        g2 = hi_mask(av1.z), g3 = hi_mask(av1.w);
            *(uint2*)&sA[nb][0][aw1] = make_uint2(pkrtz(g0, g1), pkrtz(g2, g3));
            *(uint2*)&sA[nb][1][aw1] = make_uint2(pkrtz(av1.x - g0, av1.y - g1),
                                                  pkrtz(av1.z - g2, av1.w - g3));
            *(uint4*)&sB[nb][bw0] = bv0;
            *(uint4*)&sB[nb][bw1] = bv1;
        }
        __syncthreads();
    }

    // epilogue: reduce wg1 into wg0 through LDS, write C
    unsigned char* red = &sA[0][0][0];   // 64 KB scratch (loop done)
    const int fbase = (wave & 7) * 8192;
    if (wg == 1) {
        #pragma unroll
        for (int mt = 0; mt < 4; ++mt)
            #pragma unroll
            for (int nt = 0; nt < 2; ++nt)
                *(f32x4*)&red[fbase + (mt * 2 + nt) * 1024 + lane * 16] = acc[mt][nt];
    }
    __syncthreads();
    if (wg == 0) {
        #pragma unroll
        for (int mt = 0; mt < 4; ++mt) {
            #pragma unroll
            for (int nt = 0; nt < 2; ++nt) {
                f32x4 o = acc[mt][nt] +
                          *(const f32x4*)&red[fbase + (mt * 2 + nt) * 1024 + lane * 16];
                const int r0 = row0 + wr * 64 + mt * 16 + (lane >> 4) * 4;
                const int cc = cb * 128 + wc * 32 + nt * 16 + (lane & 15);
                #pragma unroll
                for (int r = 0; r < 4; ++r)
                    C[(size_t)(r0 + r) * NE + cc] = o[r];
            }
        }
    }
}

// ---------------- Router: per-token top-k (verified rounds 1-2) -------------
__global__ __launch_bounds__(256) void router_topk_kernel(
    const float* __restrict__ logits, const float* __restrict__ bias,
    float* __restrict__ out_w, float* __restrict__ out_i)
{
    const int wid  = threadIdx.x >> 6;
    const int lane = threadIdx.x & 63;
    const int token = blockIdx.x * 4 + wid;

    const float* row = logits + (size_t)token * NE;
    const float4 lg = *(const float4*)&row[lane * 4];

    float sig[4], sc[4];
    {
        const float l4[4] = {lg.x, lg.y, lg.z, lg.w};
        #pragma unroll
        for (int j = 0; j < 4; ++j) {
            sig[j] = 1.f / (1.f + expf(-l4[j]));
            sc[j]  = sig[j] + bias[lane * 4 + j];
        }
    }

    float m1 = sc[0], m2 = -INFINITY;
    #pragma unroll
    for (int j = 1; j < 4; ++j) {
        if (sc[j] > m1) { m2 = m1; m1 = sc[j]; }
        else if (sc[j] > m2) { m2 = sc[j]; }
    }
    #pragma unroll
    for (int off = 1; off < 8; off <<= 1) {
        const float o1 = __shfl_xor(m1, off);
        const float o2 = __shfl_xor(m2, off);
        const float lo = fminf(m1, o1);
        m1 = fmaxf(m1, o1);
        m2 = fmaxf(lo, fmaxf(m2, o2));
    }
    const float gscore = m1 + m2;

    const int gmy = lane >> 3;
    int rank = 0;
    #pragma unroll
    for (int g = 0; g < NGRP; ++g) {
        const float gs = __shfl(gscore, g * 8);
        if (gs > gscore || (gs == gscore && g < gmy)) ++rank;
    }
    if (rank >= TOPG) {
        #pragma unroll
        for (int j = 0; j < 4; ++j) sc[j] = -INFINITY;
    }

    float wk[TOPK]; int ik[TOPK];
    float wsum = 0.f;
    #pragma unroll
    for (int k = 0; k < TOPK; ++k) {
        float bv = sc[0]; int bi = lane * 4;
        #pragma unroll
        for (int j = 1; j < 4; ++j)
            if (sc[j] > bv) { bv = sc[j]; bi = lane * 4 + j; }
        #pragma unroll
        for (int off = 1; off < 64; off <<= 1) {
            const float v2 = __shfl_xor(bv, off);
            const int   i2 = __shfl_xor(bi, off);
            if (v2 > bv || (v2 == bv && i2 < bi)) { bv = v2; bi = i2; }
        }
        const int owner = bi >> 2;
        const int j = bi & 3;
        const float sv = (j == 0) ? sig[0] : (j == 1) ? sig[1] : (j == 2) ? sig[2] : sig[3];
        const float w = __shfl(sv, owner);
        wk[k] = w; ik[k] = bi; wsum += w;
        if (lane == owner) {
            if (j == 0) sc[0] = -INFINITY;
            else if (j == 1) sc[1] = -INFINITY;
            else if (j == 2) sc[2] = -INFINITY;
            else sc[3] = -INFINITY;
        }
    }

    if (lane == 0) {
        const float denom = wsum + 1e-20f;
        #pragma unroll
        for (int k = 0; k < TOPK; ++k) {
            out_w[(size_t)token * TOPK + k] = wk[k] / denom;
            out_i[(size_t)token * TOPK + k] = (float)ik[k];
        }
    }
}

extern "C" void kernel_launch(void* const* d_in, const int* in_sizes, int n_in,
                              void* d_out, int out_size, void* d_ws, size_t ws_size,
                              hipStream_t stream) {
    const float* hidden = (const float*)d_in[0];
    const float* weight = (const float*)d_in[1];
    const float* bias   = (const float*)d_in[2];

    float* logits = (float*)d_out;                              // [T, E]
    float* out_w  = logits + (size_t)TKN * NE;                  // [T, 8]
    float* out_i  = out_w + (size_t)TKN * TOPK;                 // [T, 8]

    unsigned char* bpl = (unsigned char*)d_ws;                  // 4 MB B planes

    prep_b<<<512, 256, 0, stream>>>(weight, bpl);
    gemm_mfma<<<256, 1024, 0, stream>>>(hidden, bpl, logits);
    router_topk_kernel<<<TKN / 4, 256, 0, stream>>>(logits, bias, out_w, out_i);
}